// Round 9
// baseline (1403.728 us; speedup 1.0000x reference)
//
#include <hip/hip_runtime.h>
#include <hip/hip_bf16.h>

typedef __attribute__((ext_vector_type(8))) __bf16 bf16x8;
typedef __attribute__((ext_vector_type(4))) __bf16 bf16x4;
typedef __attribute__((ext_vector_type(4))) float f32x4;

#define SEQ 128
#define DIM 1024
#define BATCH 128
#define MTOT (BATCH * SEQ)   // 16384

// async global -> LDS, 16B per lane (global_load_lds_dwordx4)
__device__ __forceinline__ void gload16(const void* g, void* l) {
    __builtin_amdgcn_global_load_lds(
        (const __attribute__((address_space(1))) void*)g,
        (__attribute__((address_space(3))) void*)l, 16, 0, 0);
}

#define BARRIER() do { asm volatile("" ::: "memory"); __builtin_amdgcn_s_barrier(); asm volatile("" ::: "memory"); } while (0)
#define WAITV(N) asm volatile("s_waitcnt vmcnt(" #N ")" ::: "memory")
#define MFMA(a, b, c) __builtin_amdgcn_mfma_f32_16x16x32_bf16(a, b, c, 0, 0, 0)

// ---------------- one-launch cast: x (y=0) + 4 weight matrices (y=1) ----------------
__global__ void cast_all(const float* __restrict__ x,
                         const float* __restrict__ Wq, const float* __restrict__ Wk,
                         const float* __restrict__ Wv, const float* __restrict__ Wo,
                         __bf16* __restrict__ Xb,
                         __bf16* __restrict__ Wqb, __bf16* __restrict__ Wkb,
                         __bf16* __restrict__ Wvb, __bf16* __restrict__ Wob) {
    const float* src; __bf16* dst; size_t base;
    if (blockIdx.y == 0) {
        src = x; dst = Xb; base = (size_t)blockIdx.x * 2048;
    } else {
        const int j = blockIdx.x;
        if (j >= 2048) return;
        const int w = j >> 9;
        src = (w == 0) ? Wq : (w == 1) ? Wk : (w == 2) ? Wv : Wo;
        dst = (w == 0) ? Wqb : (w == 1) ? Wkb : (w == 2) ? Wvb : Wob;
        base = (size_t)(j & 511) * 2048;
    }
    const size_t i = base + (size_t)threadIdx.x * 8;
    float4 f0 = *reinterpret_cast<const float4*>(src + i);
    float4 f1 = *reinterpret_cast<const float4*>(src + i + 4);
    bf16x8 o;
    o[0] = (__bf16)f0.x; o[1] = (__bf16)f0.y; o[2] = (__bf16)f0.z; o[3] = (__bf16)f0.w;
    o[4] = (__bf16)f1.x; o[5] = (__bf16)f1.y; o[6] = (__bf16)f1.z; o[7] = (__bf16)f1.w;
    *reinterpret_cast<bf16x8*>(dst + i) = o;
}

// ======== 256x256-tile body (8 A-frags x 4 B-frags = 32 MFMA per BK=32) ========
#define GEMM_TILE_BODY(RB, SB, TS, DOSTAGE, VMSTMT) do { \
    const __bf16* As_ = &lds[RB][wr][0]; \
    const __bf16* Bs_ = &lds[RB][2 + (wc >> 1)][0]; \
    const int bb_ = (wc & 1) * 64; \
    bf16x8 a0 = LDF(As_, 0 * 16 + lr), a1 = LDF(As_, 1 * 16 + lr); \
    bf16x8 a2 = LDF(As_, 2 * 16 + lr), a3 = LDF(As_, 3 * 16 + lr); \
    bf16x8 a4 = LDF(As_, 4 * 16 + lr), a5 = LDF(As_, 5 * 16 + lr); \
    bf16x8 a6 = LDF(As_, 6 * 16 + lr), a7 = LDF(As_, 7 * 16 + lr); \
    bf16x8 b0 = LDF(Bs_, bb_ + 0 * 16 + lr), b1 = LDF(Bs_, bb_ + 1 * 16 + lr); \
    bf16x8 b2 = LDF(Bs_, bb_ + 2 * 16 + lr), b3 = LDF(Bs_, bb_ + 3 * 16 + lr); \
    if (DOSTAGE) { STAGE_A(SB, TS); STAGE_B(SB, TS); } \
    __builtin_amdgcn_s_setprio(1); \
    acc[0][0] = MFMA(a0, b0, acc[0][0]); acc[0][1] = MFMA(a0, b1, acc[0][1]); \
    acc[0][2] = MFMA(a0, b2, acc[0][2]); acc[0][3] = MFMA(a0, b3, acc[0][3]); \
    acc[1][0] = MFMA(a1, b0, acc[1][0]); acc[1][1] = MFMA(a1, b1, acc[1][1]); \
    acc[1][2] = MFMA(a1, b2, acc[1][2]); acc[1][3] = MFMA(a1, b3, acc[1][3]); \
    acc[2][0] = MFMA(a2, b0, acc[2][0]); acc[2][1] = MFMA(a2, b1, acc[2][1]); \
    acc[2][2] = MFMA(a2, b2, acc[2][2]); acc[2][3] = MFMA(a2, b3, acc[2][3]); \
    acc[3][0] = MFMA(a3, b0, acc[3][0]); acc[3][1] = MFMA(a3, b1, acc[3][1]); \
    acc[3][2] = MFMA(a3, b2, acc[3][2]); acc[3][3] = MFMA(a3, b3, acc[3][3]); \
    acc[4][0] = MFMA(a4, b0, acc[4][0]); acc[4][1] = MFMA(a4, b1, acc[4][1]); \
    acc[4][2] = MFMA(a4, b2, acc[4][2]); acc[4][3] = MFMA(a4, b3, acc[4][3]); \
    acc[5][0] = MFMA(a5, b0, acc[5][0]); acc[5][1] = MFMA(a5, b1, acc[5][1]); \
    acc[5][2] = MFMA(a5, b2, acc[5][2]); acc[5][3] = MFMA(a5, b3, acc[5][3]); \
    acc[6][0] = MFMA(a6, b0, acc[6][0]); acc[6][1] = MFMA(a6, b1, acc[6][1]); \
    acc[6][2] = MFMA(a6, b2, acc[6][2]); acc[6][3] = MFMA(a6, b3, acc[6][3]); \
    acc[7][0] = MFMA(a7, b0, acc[7][0]); acc[7][1] = MFMA(a7, b1, acc[7][1]); \
    acc[7][2] = MFMA(a7, b2, acc[7][2]); acc[7][3] = MFMA(a7, b3, acc[7][3]); \
    __builtin_amdgcn_s_setprio(0); \
    VMSTMT; \
    BARRIER(); \
} while (0)

// ---------------- fused QKV GEMM: 256x256 tiles, 2-buf double-buffer, 2 blocks/CU ----------------
// Grid 768: XCD-swizzled logical = mt*12 + nt; nt>>2 selects {Q,K,V}; V written per-batch transposed.
__global__ __launch_bounds__(512, 4) void gemm_qkv3(const __bf16* __restrict__ A,
        const __bf16* __restrict__ Wqb, const __bf16* __restrict__ Wkb, const __bf16* __restrict__ Wvb,
        const float* __restrict__ bq, const float* __restrict__ bk, const float* __restrict__ bv,
        __bf16* __restrict__ Qo, __bf16* __restrict__ Ko, __bf16* __restrict__ Vt) {
    const int K = 1024;
    __shared__ __bf16 lds[2][4][4096];   // 64KB -> 2 blocks/CU
    const int tid = threadIdx.x, wave = tid >> 6, lane = tid & 63;
    const int wr = wave >> 2, wc = wave & 3;
    const int lr = lane & 15;
    const int lkb = ((lane >> 4) & 3) * 16;
    const unsigned bid = blockIdx.x;
    const unsigned swz = (bid & 7) * 96 + (bid >> 3);
    const int mt = swz / 12, nt = swz % 12;
    const int m0 = mt * 256;
    const int n0row = (nt & 3) * 256;
    const int mid = nt >> 2;                  // 0=Q 1=K 2=V
    const __bf16* Wsel = (mid == 0) ? Wqb : (mid == 1) ? Wkb : Wvb;
    const float*  bsel = (mid == 0) ? bq  : (mid == 1) ? bk  : bv;

    const int rloc = wave * 16 + (lane >> 2);
    const int cbs  = ((((lane & 3) << 4) ^ (((lane >> 3) & 3) << 4)) >> 1);
    const __bf16* pA = A + (size_t)(m0 + rloc) * K + cbs;
    const __bf16* pB = Wsel + (size_t)(n0row + rloc) * K + cbs;
    const int wo = wave * 512;

    f32x4 acc[8][4] = {};

#define LDF(SLOT, R) (*reinterpret_cast<const bf16x8*>( \
        reinterpret_cast<const char*>(SLOT) + (R) * 64 + (lkb ^ ((((R) >> 1) & 3) << 4))))
#define STAGE_A(SB, TS) do { gload16(pA + (TS) * 32, &lds[SB][0][wo]); \
                             gload16(pA + (size_t)128 * 1024 + (TS) * 32, &lds[SB][1][wo]); } while (0)
#define STAGE_B(SB, TS) do { gload16(pB + (TS) * 32, &lds[SB][2][wo]); \
                             gload16(pB + (size_t)128 * 1024 + (TS) * 32, &lds[SB][3][wo]); } while (0)

    STAGE_A(0, 0); STAGE_B(0, 0);
    WAITV(0);
    BARRIER();

    for (int it = 0; it < 15; ++it) {
        GEMM_TILE_BODY(0, 1, 2 * it + 1, 1, WAITV(0));
        GEMM_TILE_BODY(1, 0, 2 * it + 2, 1, WAITV(0));
    }
    GEMM_TILE_BODY(0, 1, 31, 1, WAITV(0));
    GEMM_TILE_BODY(1, 0, 0, 0, (void)0);

    const int rbase = (lane >> 4) * 4;
    #pragma unroll
    for (int ri = 0; ri < 8; ++ri) {
        #pragma unroll
        for (int j = 0; j < 4; ++j) {
            const int gcl = n0row + wc * 64 + j * 16 + lr;
            const float bvv = bsel[gcl];
            const int grb = m0 + wr * 128 + ri * 16 + rbase;
            if (mid < 2) {
                __bf16* C = (mid == 0) ? Qo : Ko;
                #pragma unroll
                for (int r = 0; r < 4; ++r)
                    C[(size_t)(grb + r) * DIM + gcl] = (__bf16)(acc[ri][j][r] + bvv);
            } else {
                const int b = grb >> 7, s = grb & 127;
                bf16x4 v;
                #pragma unroll
                for (int r = 0; r < 4; ++r) v[r] = (__bf16)(acc[ri][j][r] + bvv);
                *reinterpret_cast<bf16x4*>(&Vt[((size_t)b * DIM + gcl) * SEQ + s]) = v;
            }
        }
    }
#undef STAGE_A
#undef STAGE_B
#undef LDF
}

// ---------------- output GEMM: 128x256 tiles, 2-buf, 2 blocks/CU, f32 out ----------------
// Grid 512 = 128 m-tiles x 4 n-tiles, XCD-swizzled.
__global__ __launch_bounds__(512, 4) void gemm_out(const __bf16* __restrict__ A,
                                                   const __bf16* __restrict__ W,
                                                   const float* __restrict__ bias,
                                                   float* __restrict__ Cout) {
    const int K = 1024, N = 1024;
    __shared__ __bf16 lds[2][3][4096];   // 48KB: [buf][A, B0, B1][128 rows x 32 k]
    const int tid = threadIdx.x, wave = tid >> 6, lane = tid & 63;
    const int wr = wave >> 2, wc = wave & 3;     // 2x4 wave grid; wave tile 64x64
    const int lr = lane & 15;
    const int lkb = ((lane >> 4) & 3) * 16;
    const int bid = blockIdx.x;
    const int swz = (bid & 7) * 64 + (bid >> 3);
    const int mt = swz >> 2, nt = swz & 3;
    const int m0 = mt * 128, n0 = nt * 256;
    const int rloc = wave * 16 + (lane >> 2);    // 0..127
    const int cbs  = ((((lane & 3) << 4) ^ (((lane >> 3) & 3) << 4)) >> 1);
    const __bf16* pA = A + (size_t)(m0 + rloc) * K + cbs;
    const __bf16* pB = W + (size_t)(n0 + rloc) * K + cbs;
    const int wo = wave * 512;

    f32x4 acc[4][4] = {};

#define LDF(SLOT, R) (*reinterpret_cast<const bf16x8*>( \
        reinterpret_cast<const char*>(SLOT) + (R) * 64 + (lkb ^ ((((R) >> 1) & 3) << 4))))
#define OSTAGE(SB, TS) do { gload16(pA + (TS) * 32, &lds[SB][0][wo]); \
                            gload16(pB + (TS) * 32, &lds[SB][1][wo]); \
                            gload16(pB + (size_t)128 * 1024 + (TS) * 32, &lds[SB][2][wo]); } while (0)

#define OTILE(RB, SB, TS, DOSTAGE, VMSTMT) do { \
    const __bf16* As_ = &lds[RB][0][0]; \
    const __bf16* Bs_ = &lds[RB][1 + (wc >> 1)][0]; \
    const int bb_ = (wc & 1) * 64; \
    const int ab_ = wr * 64; \
    bf16x8 a0 = LDF(As_, ab_ + 0 * 16 + lr), a1 = LDF(As_, ab_ + 1 * 16 + lr); \
    bf16x8 a2 = LDF(As_, ab_ + 2 * 16 + lr), a3 = LDF(As_, ab_ + 3 * 16 + lr); \
    bf16x8 b0 = LDF(Bs_, bb_ + 0 * 16 + lr), b1 = LDF(Bs_, bb_ + 1 * 16 + lr); \
    bf16x8 b2 = LDF(Bs_, bb_ + 2 * 16 + lr), b3 = LDF(Bs_, bb_ + 3 * 16 + lr); \
    if (DOSTAGE) OSTAGE(SB, TS); \
    __builtin_amdgcn_s_setprio(1); \
    acc[0][0] = MFMA(a0, b0, acc[0][0]); acc[0][1] = MFMA(a0, b1, acc[0][1]); \
    acc[0][2] = MFMA(a0, b2, acc[0][2]); acc[0][3] = MFMA(a0, b3, acc[0][3]); \
    acc[1][0] = MFMA(a1, b0, acc[1][0]); acc[1][1] = MFMA(a1, b1, acc[1][1]); \
    acc[1][2] = MFMA(a1, b2, acc[1][2]); acc[1][3] = MFMA(a1, b3, acc[1][3]); \
    acc[2][0] = MFMA(a2, b0, acc[2][0]); acc[2][1] = MFMA(a2, b1, acc[2][1]); \
    acc[2][2] = MFMA(a2, b2, acc[2][2]); acc[2][3] = MFMA(a2, b3, acc[2][3]); \
    acc[3][0] = MFMA(a3, b0, acc[3][0]); acc[3][1] = MFMA(a3, b1, acc[3][1]); \
    acc[3][2] = MFMA(a3, b2, acc[3][2]); acc[3][3] = MFMA(a3, b3, acc[3][3]); \
    __builtin_amdgcn_s_setprio(0); \
    VMSTMT; \
    BARRIER(); \
} while (0)

    OSTAGE(0, 0);
    WAITV(0);
    BARRIER();

    for (int it = 0; it < 15; ++it) {
        OTILE(0, 1, 2 * it + 1, 1, WAITV(0));
        OTILE(1, 0, 2 * it + 2, 1, WAITV(0));
    }
    OTILE(0, 1, 31, 1, WAITV(0));
    OTILE(1, 0, 0, 0, (void)0);

    const int rbase = (lane >> 4) * 4;
    #pragma unroll
    for (int ri = 0; ri < 4; ++ri) {
        #pragma unroll
        for (int j = 0; j < 4; ++j) {
            const int gc  = n0 + wc * 64 + j * 16 + lr;
            const float bv = bias[gc];
            const int grb = m0 + wr * 64 + ri * 16 + rbase;
            #pragma unroll
            for (int r = 0; r < 4; ++r)
                Cout[(size_t)(grb + r) * N + gc] = acc[ri][j][r] + bv;
        }
    }
#undef OTILE
#undef OSTAGE
#undef LDF
}

// ---------------- fused attention, LDS-pipelined (unchanged) ----------------
__global__ __launch_bounds__(256) void attn_kernel(const __bf16* __restrict__ Q,
                                                   const __bf16* __restrict__ Km,
                                                   const __bf16* __restrict__ Vt,
                                                   __bf16* __restrict__ Ab) {
    __shared__ __align__(16) char smem[40960];
    float  (*Ssh)[132] = (float(*)[132])(smem);            // [32][132] f32
    __bf16 (*Psh)[136] = (__bf16(*)[136])(smem + 16896);   // [32][136] bf16

    const int bid = blockIdx.x;
    const int logical = (bid & 7) * 64 + (bid >> 3);
    const int b = logical >> 2, rt = logical & 3;
    const int tid = threadIdx.x, wave = tid >> 6, lane = tid & 63;
    const int lr = lane & 15, lk = (lane >> 4) * 8, rbase = (lane >> 4) * 4;
    const __bf16* Qb = Q  + ((size_t)b * SEQ + rt * 32) * DIM;
    const __bf16* Kb = Km + (size_t)b * SEQ * DIM;
    const __bf16* Vb = Vt + (size_t)b * DIM * SEQ;

    const int csrc = ((lane & 7) * 16) ^ (((lane >> 3) & 7) << 4);

    // ---- phase 1: S = Q K^T, chunks of BK=64 ----
    f32x4 acc[2][2] = {};
    {
        auto stage_kq = [&](int buf, int c) {
            char* Kd = smem + buf * 20480 + wave * 4096;
            char* Qd = smem + buf * 20480 + 16384 + wave * 1024;
            const char* Ks = (const char*)Kb + (size_t)(wave * 32 + (lane >> 3)) * 2048 + c * 128 + csrc;
            #pragma unroll
            for (int q = 0; q < 4; ++q)
                gload16(Ks + (size_t)q * 8 * 2048, Kd + q * 1024);
            const char* Qs = (const char*)Qb + (size_t)(wave * 8 + (lane >> 3)) * 2048 + c * 128 + csrc;
            gload16(Qs, Qd);
        };
        stage_kq(0, 0);
        WAITV(0);
        BARRIER();
        for (int c = 0; c < 16; ++c) {
            const int rb = c & 1;
            if (c < 15) stage_kq(rb ^ 1, c + 1);
            const char* Kl = smem + rb * 20480;
            const char* Ql = Kl + 16384;
            bf16x8 qf[2][2], kf[2][2];
            #pragma unroll
            for (int i = 0; i < 2; ++i)
                #pragma unroll
                for (int ks = 0; ks < 2; ++ks) {
                    const int r = i * 16 + lr;
                    qf[i][ks] = *reinterpret_cast<const bf16x8*>(
                        Ql + r * 128 + ((ks * 64 + (lane >> 4) * 16) ^ ((r & 7) << 4)));
                }
            #pragma unroll
            for (int j = 0; j < 2; ++j)
                #pragma unroll
                for (int ks = 0; ks < 2; ++ks) {
                    const int r = wave * 32 + j * 16 + lr;
                    kf[j][ks] = *reinterpret_cast<const bf16x8*>(
                        Kl + r * 128 + ((ks * 64 + (lane >> 4) * 16) ^ ((r & 7) << 4)));
                }
            __builtin_amdgcn_s_setprio(1);
            #pragma unroll
            for (int i = 0; i < 2; ++i)
                #pragma unroll
                for (int j = 0; j < 2; ++j)
                    #pragma unroll
                    for (int ks = 0; ks < 2; ++ks)
                        acc[i][j] = MFMA(qf[i][ks], kf[j][ks], acc[i][j]);
            __builtin_amdgcn_s_setprio(0);
            WAITV(0);
            BARRIER();
        }
    }
    const float scale = 0.03125f;  // 1/sqrt(1024)
    #pragma unroll
    for (int i = 0; i < 2; ++i)
        #pragma unroll
        for (int j = 0; j < 2; ++j)
            #pragma unroll
            for (int r = 0; r < 4; ++r)
                Ssh[i * 16 + rbase + r][wave * 32 + j * 16 + lr] = acc[i][j][r] * scale;
    __syncthreads();

    // ---- wave-parallel softmax ----
    {
        const int row = tid >> 3;
        const int c0  = (tid & 7) * 16;
        float4 v0 = *reinterpret_cast<const float4*>(&Ssh[row][c0]);
        float4 v1 = *reinterpret_cast<const float4*>(&Ssh[row][c0 + 4]);
        float4 v2 = *reinterpret_cast<const float4*>(&Ssh[row][c0 + 8]);
        float4 v3 = *reinterpret_cast<const float4*>(&Ssh[row][c0 + 12]);
        float e[16] = {v0.x, v0.y, v0.z, v0.w, v1.x, v1.y, v1.z, v1.w,
                       v2.x, v2.y, v2.z, v2.w, v3.x, v3.y, v3.z, v3.w};
        float mx = e[0];
        #pragma unroll
        for (int u = 1; u < 16; ++u) mx = fmaxf(mx, e[u]);
        mx = fmaxf(mx, __shfl_xor(mx, 1));
        mx = fmaxf(mx, __shfl_xor(mx, 2));
        mx = fmaxf(mx, __shfl_xor(mx, 4));
        float s = 0.f;
        #pragma unroll
        for (int u = 0; u < 16; ++u) { e[u] = __expf(e[u] - mx); s += e[u]; }
        s += __shfl_xor(s, 1);
        s += __shfl_xor(s, 2);
        s += __shfl_xor(s, 4);
        const float inv = 1.f / s;
        bf16x8 p0, p1;
        #pragma unroll
        for (int u = 0; u < 8; ++u) { p0[u] = (__bf16)(e[u] * inv); p1[u] = (__bf16)(e[u + 8] * inv); }
        *reinterpret_cast<bf16x8*>(&Psh[row][c0])     = p0;
        *reinterpret_cast<bf16x8*>(&Psh[row][c0 + 8]) = p1;
    }
    __syncthreads();

    bf16x8 pf[2][4];
    #pragma unroll
    for (int i = 0; i < 2; ++i)
        #pragma unroll
        for (int ks = 0; ks < 4; ++ks)
            pf[i][ks] = *reinterpret_cast<const bf16x8*>(&Psh[i * 16 + lr][ks * 32 + lk]);
    __syncthreads();   // pf safe in regs before buffers reused

    // ---- phase 2: att = P V ----
    __bf16* Ao = Ab + ((size_t)b * SEQ + rt * 32) * DIM;
    {
        auto stage_v = [&](int buf, int c) {
            char* Vd = smem + buf * 16384 + wave * 4096;
            #pragma unroll
            for (int q = 0; q < 4; ++q) {
                const int rowl = wave * 16 + q * 4 + (lane >> 4);
                const char* Vs = (const char*)Vb + (size_t)(c * 64 + rowl) * 256 +
                                 (((lane & 15) * 16) ^ ((rowl & 7) << 4));
                gload16(Vs, Vd + q * 1024);
            }
        };
        stage_v(0, 0);
        WAITV(0);
        BARRIER();
        for (int c = 0; c < 16; ++c) {
            const int rb = c & 1;
            if (c < 15) stage_v(rb ^ 1, c + 1);
            const char* Vl = smem + rb * 16384;
            f32x4 a2[2] = {};
            const int r = wave * 16 + lr;
            #pragma unroll
            for (int ks = 0; ks < 4; ++ks) {
                bf16x8 vf = *reinterpret_cast<const bf16x8*>(
                    Vl + r * 256 + ((ks * 64 + (lane >> 4) * 16) ^ ((r & 7) << 4)));
                a2[0] = MFMA(pf[0][ks], vf, a2[0]);
                a2[1] = MFMA(pf[1][ks], vf, a2[1]);
            }
            const int n0 = c * 64 + wave * 16;
            #pragma unroll
            for (int i = 0; i < 2; ++i)
                #pragma unroll
                for (int rr = 0; rr < 4; ++rr)
                    Ao[(size_t)(i * 16 + rbase + rr) * DIM + n0 + lr] = (__bf16)a2[i][rr];
            WAITV(8);
            BARRIER();
        }
    }
}

extern "C" void kernel_launch(void* const* d_in, const int* in_sizes, int n_in,
                              void* d_out, int out_size, void* d_ws, size_t ws_size,
                              hipStream_t stream) {
    const float* x  = (const float*)d_in[0];
    const float* Wq = (const float*)d_in[1];
    const float* bq = (const float*)d_in[2];
    const float* Wk = (const float*)d_in[3];
    const float* bk = (const float*)d_in[4];
    const float* Wv = (const float*)d_in[5];
    const float* bv = (const float*)d_in[6];
    const float* Wo = (const float*)d_in[7];
    const float* bo = (const float*)d_in[8];

    char* ws = (char*)d_ws;
    const size_t MB = 1024 * 1024;
    __bf16* Xb  = (__bf16*)(ws);              // 32MB; reused as Ab after QKV GEMM
    __bf16* Wqb = (__bf16*)(ws + 32 * MB);    // 2MB each
    __bf16* Wkb = (__bf16*)(ws + 34 * MB);
    __bf16* Wvb = (__bf16*)(ws + 36 * MB);
    __bf16* Wob = (__bf16*)(ws + 38 * MB);
    __bf16* Qb  = (__bf16*)(ws + 40 * MB);    // 32MB
    __bf16* Kb  = (__bf16*)(ws + 72 * MB);    // 32MB
    __bf16* Vt  = (__bf16*)(ws + 104 * MB);   // 32MB
    __bf16* Ab  = Xb;

    cast_all<<<dim3(8192, 2), 256, 0, stream>>>(x, Wq, Wk, Wv, Wo, Xb, Wqb, Wkb, Wvb, Wob);

    gemm_qkv3<<<768, 512, 0, stream>>>(Xb, Wqb, Wkb, Wvb, bq, bk, bv, Qb, Kb, Vt);

    attn_kernel<<<512, 256, 0, stream>>>(Qb, Kb, Vt, Ab);

    gemm_out<<<512, 512, 0, stream>>>(Ab, Wob, bo, (float*)d_out);
}

// Round 10
// 199.780 us; speedup vs baseline: 7.0264x; 7.0264x over previous
//
#include <hip/hip_runtime.h>
#include <hip/hip_bf16.h>

typedef __attribute__((ext_vector_type(8))) __bf16 bf16x8;
typedef __attribute__((ext_vector_type(4))) __bf16 bf16x4;
typedef __attribute__((ext_vector_type(4))) float f32x4;

#define SEQ 128
#define DIM 1024
#define BATCH 128
#define MTOT (BATCH * SEQ)   // 16384

// async global -> LDS, 16B per lane (global_load_lds_dwordx4)
__device__ __forceinline__ void gload16(const void* g, void* l) {
    __builtin_amdgcn_global_load_lds(
        (const __attribute__((address_space(1))) void*)g,
        (__attribute__((address_space(3))) void*)l, 16, 0, 0);
}

#define BARRIER() do { asm volatile("" ::: "memory"); __builtin_amdgcn_s_barrier(); asm volatile("" ::: "memory"); } while (0)
#define WAITV(N) asm volatile("s_waitcnt vmcnt(" #N ")" ::: "memory")
#define MFMA(a, b, c) __builtin_amdgcn_mfma_f32_16x16x32_bf16(a, b, c, 0, 0, 0)

// ---------------- one-launch cast: x (y=0) + 4 weight matrices (y=1) ----------------
__global__ void cast_all(const float* __restrict__ x,
                         const float* __restrict__ Wq, const float* __restrict__ Wk,
                         const float* __restrict__ Wv, const float* __restrict__ Wo,
                         __bf16* __restrict__ Xb,
                         __bf16* __restrict__ Wqb, __bf16* __restrict__ Wkb,
                         __bf16* __restrict__ Wvb, __bf16* __restrict__ Wob) {
    const float* src; __bf16* dst; size_t base;
    if (blockIdx.y == 0) {
        src = x; dst = Xb; base = (size_t)blockIdx.x * 2048;
    } else {
        const int j = blockIdx.x;
        if (j >= 2048) return;
        const int w = j >> 9;
        src = (w == 0) ? Wq : (w == 1) ? Wk : (w == 2) ? Wv : Wo;
        dst = (w == 0) ? Wqb : (w == 1) ? Wkb : (w == 2) ? Wvb : Wob;
        base = (size_t)(j & 511) * 2048;
    }
    const size_t i = base + (size_t)threadIdx.x * 8;
    float4 f0 = *reinterpret_cast<const float4*>(src + i);
    float4 f1 = *reinterpret_cast<const float4*>(src + i + 4);
    bf16x8 o;
    o[0] = (__bf16)f0.x; o[1] = (__bf16)f0.y; o[2] = (__bf16)f0.z; o[3] = (__bf16)f0.w;
    o[4] = (__bf16)f1.x; o[5] = (__bf16)f1.y; o[6] = (__bf16)f1.z; o[7] = (__bf16)f1.w;
    *reinterpret_cast<bf16x8*>(dst + i) = o;
}

// ======== 256x256-tile body (8 A-frags x 4 B-frags = 32 MFMA per BK=32) ========
#define GEMM_TILE_BODY(RB, SB, TS, DOSTAGE, VMSTMT) do { \
    const __bf16* As_ = &lds[RB][wr][0]; \
    const __bf16* Bs_ = &lds[RB][2 + (wc >> 1)][0]; \
    const int bb_ = (wc & 1) * 64; \
    bf16x8 a0 = LDF(As_, 0 * 16 + lr), a1 = LDF(As_, 1 * 16 + lr); \
    bf16x8 a2 = LDF(As_, 2 * 16 + lr), a3 = LDF(As_, 3 * 16 + lr); \
    bf16x8 a4 = LDF(As_, 4 * 16 + lr), a5 = LDF(As_, 5 * 16 + lr); \
    bf16x8 a6 = LDF(As_, 6 * 16 + lr), a7 = LDF(As_, 7 * 16 + lr); \
    bf16x8 b0 = LDF(Bs_, bb_ + 0 * 16 + lr), b1 = LDF(Bs_, bb_ + 1 * 16 + lr); \
    bf16x8 b2 = LDF(Bs_, bb_ + 2 * 16 + lr), b3 = LDF(Bs_, bb_ + 3 * 16 + lr); \
    if (DOSTAGE) { STAGE_A(SB, TS); STAGE_B(SB, TS); } \
    __builtin_amdgcn_s_setprio(1); \
    acc[0][0] = MFMA(a0, b0, acc[0][0]); acc[0][1] = MFMA(a0, b1, acc[0][1]); \
    acc[0][2] = MFMA(a0, b2, acc[0][2]); acc[0][3] = MFMA(a0, b3, acc[0][3]); \
    acc[1][0] = MFMA(a1, b0, acc[1][0]); acc[1][1] = MFMA(a1, b1, acc[1][1]); \
    acc[1][2] = MFMA(a1, b2, acc[1][2]); acc[1][3] = MFMA(a1, b3, acc[1][3]); \
    acc[2][0] = MFMA(a2, b0, acc[2][0]); acc[2][1] = MFMA(a2, b1, acc[2][1]); \
    acc[2][2] = MFMA(a2, b2, acc[2][2]); acc[2][3] = MFMA(a2, b3, acc[2][3]); \
    acc[3][0] = MFMA(a3, b0, acc[3][0]); acc[3][1] = MFMA(a3, b1, acc[3][1]); \
    acc[3][2] = MFMA(a3, b2, acc[3][2]); acc[3][3] = MFMA(a3, b3, acc[3][3]); \
    acc[4][0] = MFMA(a4, b0, acc[4][0]); acc[4][1] = MFMA(a4, b1, acc[4][1]); \
    acc[4][2] = MFMA(a4, b2, acc[4][2]); acc[4][3] = MFMA(a4, b3, acc[4][3]); \
    acc[5][0] = MFMA(a5, b0, acc[5][0]); acc[5][1] = MFMA(a5, b1, acc[5][1]); \
    acc[5][2] = MFMA(a5, b2, acc[5][2]); acc[5][3] = MFMA(a5, b3, acc[5][3]); \
    acc[6][0] = MFMA(a6, b0, acc[6][0]); acc[6][1] = MFMA(a6, b1, acc[6][1]); \
    acc[6][2] = MFMA(a6, b2, acc[6][2]); acc[6][3] = MFMA(a6, b3, acc[6][3]); \
    acc[7][0] = MFMA(a7, b0, acc[7][0]); acc[7][1] = MFMA(a7, b1, acc[7][1]); \
    acc[7][2] = MFMA(a7, b2, acc[7][2]); acc[7][3] = MFMA(a7, b3, acc[7][3]); \
    __builtin_amdgcn_s_setprio(0); \
    VMSTMT; \
    BARRIER(); \
} while (0)

// ---------------- fused QKV GEMM: 256x256 tiles, 2-buf (64KB) -> 2 blocks/CU at VGPR=128 ----------------
// Grid 768: XCD-swizzled logical = mt*12 + nt; nt>>2 selects {Q,K,V}; V written per-batch transposed.
__global__ __launch_bounds__(512, 1) void gemm_qkv3(const __bf16* __restrict__ A,
        const __bf16* __restrict__ Wqb, const __bf16* __restrict__ Wkb, const __bf16* __restrict__ Wvb,
        const float* __restrict__ bq, const float* __restrict__ bk, const float* __restrict__ bv,
        __bf16* __restrict__ Qo, __bf16* __restrict__ Ko, __bf16* __restrict__ Vt) {
    const int K = 1024;
    __shared__ __bf16 lds[2][4][4096];   // 64KB
    const int tid = threadIdx.x, wave = tid >> 6, lane = tid & 63;
    const int wr = wave >> 2, wc = wave & 3;
    const int lr = lane & 15;
    const int lkb = ((lane >> 4) & 3) * 16;
    const unsigned bid = blockIdx.x;
    const unsigned swz = (bid & 7) * 96 + (bid >> 3);
    const int mt = swz / 12, nt = swz % 12;
    const int m0 = mt * 256;
    const int n0row = (nt & 3) * 256;
    const int mid = nt >> 2;                  // 0=Q 1=K 2=V
    const __bf16* Wsel = (mid == 0) ? Wqb : (mid == 1) ? Wkb : Wvb;
    const float*  bsel = (mid == 0) ? bq  : (mid == 1) ? bk  : bv;

    const int rloc = wave * 16 + (lane >> 2);
    const int cbs  = ((((lane & 3) << 4) ^ (((lane >> 3) & 3) << 4)) >> 1);
    const __bf16* pA = A + (size_t)(m0 + rloc) * K + cbs;
    const __bf16* pB = Wsel + (size_t)(n0row + rloc) * K + cbs;
    const int wo = wave * 512;

    f32x4 acc[8][4] = {};

#define LDF(SLOT, R) (*reinterpret_cast<const bf16x8*>( \
        reinterpret_cast<const char*>(SLOT) + (R) * 64 + (lkb ^ ((((R) >> 1) & 3) << 4))))
#define STAGE_A(SB, TS) do { gload16(pA + (TS) * 32, &lds[SB][0][wo]); \
                             gload16(pA + (size_t)128 * 1024 + (TS) * 32, &lds[SB][1][wo]); } while (0)
#define STAGE_B(SB, TS) do { gload16(pB + (TS) * 32, &lds[SB][2][wo]); \
                             gload16(pB + (size_t)128 * 1024 + (TS) * 32, &lds[SB][3][wo]); } while (0)

    STAGE_A(0, 0); STAGE_B(0, 0);
    WAITV(0);
    BARRIER();

    for (int it = 0; it < 15; ++it) {
        GEMM_TILE_BODY(0, 1, 2 * it + 1, 1, WAITV(0));
        GEMM_TILE_BODY(1, 0, 2 * it + 2, 1, WAITV(0));
    }
    GEMM_TILE_BODY(0, 1, 31, 1, WAITV(0));
    GEMM_TILE_BODY(1, 0, 0, 0, (void)0);

    const int rbase = (lane >> 4) * 4;
    #pragma unroll
    for (int ri = 0; ri < 8; ++ri) {
        #pragma unroll
        for (int j = 0; j < 4; ++j) {
            const int gcl = n0row + wc * 64 + j * 16 + lr;
            const float bvv = bsel[gcl];
            const int grb = m0 + wr * 128 + ri * 16 + rbase;
            if (mid < 2) {
                __bf16* C = (mid == 0) ? Qo : Ko;
                #pragma unroll
                for (int r = 0; r < 4; ++r)
                    C[(size_t)(grb + r) * DIM + gcl] = (__bf16)(acc[ri][j][r] + bvv);
            } else {
                const int b = grb >> 7, s = grb & 127;
                bf16x4 v;
                #pragma unroll
                for (int r = 0; r < 4; ++r) v[r] = (__bf16)(acc[ri][j][r] + bvv);
                *reinterpret_cast<bf16x4*>(&Vt[((size_t)b * DIM + gcl) * SEQ + s]) = v;
            }
        }
    }
#undef STAGE_A
#undef STAGE_B
#undef LDF
}

// ---------------- output GEMM: 128x256 tiles, 2-buf (48KB), f32 out ----------------
// Grid 512 = 128 m-tiles x 4 n-tiles, XCD-swizzled.
__global__ __launch_bounds__(512, 1) void gemm_out(const __bf16* __restrict__ A,
                                                   const __bf16* __restrict__ W,
                                                   const float* __restrict__ bias,
                                                   float* __restrict__ Cout) {
    const int K = 1024, N = 1024;
    __shared__ __bf16 lds[2][3][4096];   // 48KB: [buf][A, B0, B1][128 rows x 32 k]
    const int tid = threadIdx.x, wave = tid >> 6, lane = tid & 63;
    const int wr = wave >> 2, wc = wave & 3;     // 2x4 wave grid; wave tile 64x64
    const int lr = lane & 15;
    const int lkb = ((lane >> 4) & 3) * 16;
    const int bid = blockIdx.x;
    const int swz = (bid & 7) * 64 + (bid >> 3);
    const int mt = swz >> 2, nt = swz & 3;
    const int m0 = mt * 128, n0 = nt * 256;
    const int rloc = wave * 16 + (lane >> 2);    // 0..127
    const int cbs  = ((((lane & 3) << 4) ^ (((lane >> 3) & 3) << 4)) >> 1);
    const __bf16* pA = A + (size_t)(m0 + rloc) * K + cbs;
    const __bf16* pB = W + (size_t)(n0 + rloc) * K + cbs;
    const int wo = wave * 512;

    f32x4 acc[4][4] = {};

#define LDF(SLOT, R) (*reinterpret_cast<const bf16x8*>( \
        reinterpret_cast<const char*>(SLOT) + (R) * 64 + (lkb ^ ((((R) >> 1) & 3) << 4))))
#define OSTAGE(SB, TS) do { gload16(pA + (TS) * 32, &lds[SB][0][wo]); \
                            gload16(pB + (TS) * 32, &lds[SB][1][wo]); \
                            gload16(pB + (size_t)128 * 1024 + (TS) * 32, &lds[SB][2][wo]); } while (0)

#define OTILE(RB, SB, TS, DOSTAGE, VMSTMT) do { \
    const __bf16* As_ = &lds[RB][0][0]; \
    const __bf16* Bs_ = &lds[RB][1 + (wc >> 1)][0]; \
    const int bb_ = (wc & 1) * 64; \
    const int ab_ = wr * 64; \
    bf16x8 a0 = LDF(As_, ab_ + 0 * 16 + lr), a1 = LDF(As_, ab_ + 1 * 16 + lr); \
    bf16x8 a2 = LDF(As_, ab_ + 2 * 16 + lr), a3 = LDF(As_, ab_ + 3 * 16 + lr); \
    bf16x8 b0 = LDF(Bs_, bb_ + 0 * 16 + lr), b1 = LDF(Bs_, bb_ + 1 * 16 + lr); \
    bf16x8 b2 = LDF(Bs_, bb_ + 2 * 16 + lr), b3 = LDF(Bs_, bb_ + 3 * 16 + lr); \
    if (DOSTAGE) OSTAGE(SB, TS); \
    __builtin_amdgcn_s_setprio(1); \
    acc[0][0] = MFMA(a0, b0, acc[0][0]); acc[0][1] = MFMA(a0, b1, acc[0][1]); \
    acc[0][2] = MFMA(a0, b2, acc[0][2]); acc[0][3] = MFMA(a0, b3, acc[0][3]); \
    acc[1][0] = MFMA(a1, b0, acc[1][0]); acc[1][1] = MFMA(a1, b1, acc[1][1]); \
    acc[1][2] = MFMA(a1, b2, acc[1][2]); acc[1][3] = MFMA(a1, b3, acc[1][3]); \
    acc[2][0] = MFMA(a2, b0, acc[2][0]); acc[2][1] = MFMA(a2, b1, acc[2][1]); \
    acc[2][2] = MFMA(a2, b2, acc[2][2]); acc[2][3] = MFMA(a2, b3, acc[2][3]); \
    acc[3][0] = MFMA(a3, b0, acc[3][0]); acc[3][1] = MFMA(a3, b1, acc[3][1]); \
    acc[3][2] = MFMA(a3, b2, acc[3][2]); acc[3][3] = MFMA(a3, b3, acc[3][3]); \
    __builtin_amdgcn_s_setprio(0); \
    VMSTMT; \
    BARRIER(); \
} while (0)

    OSTAGE(0, 0);
    WAITV(0);
    BARRIER();

    for (int it = 0; it < 15; ++it) {
        OTILE(0, 1, 2 * it + 1, 1, WAITV(0));
        OTILE(1, 0, 2 * it + 2, 1, WAITV(0));
    }
    OTILE(0, 1, 31, 1, WAITV(0));
    OTILE(1, 0, 0, 0, (void)0);

    const int rbase = (lane >> 4) * 4;
    #pragma unroll
    for (int ri = 0; ri < 4; ++ri) {
        #pragma unroll
        for (int j = 0; j < 4; ++j) {
            const int gc  = n0 + wc * 64 + j * 16 + lr;
            const float bv = bias[gc];
            const int grb = m0 + wr * 64 + ri * 16 + rbase;
            #pragma unroll
            for (int r = 0; r < 4; ++r)
                Cout[(size_t)(grb + r) * N + gc] = acc[ri][j][r] + bv;
        }
    }
#undef OTILE
#undef OSTAGE
#undef LDF
}

// ---------------- fused attention, LDS-pipelined (unchanged) ----------------
__global__ __launch_bounds__(256) void attn_kernel(const __bf16* __restrict__ Q,
                                                   const __bf16* __restrict__ Km,
                                                   const __bf16* __restrict__ Vt,
                                                   __bf16* __restrict__ Ab) {
    __shared__ __align__(16) char smem[40960];
    float  (*Ssh)[132] = (float(*)[132])(smem);            // [32][132] f32
    __bf16 (*Psh)[136] = (__bf16(*)[136])(smem + 16896);   // [32][136] bf16

    const int bid = blockIdx.x;
    const int logical = (bid & 7) * 64 + (bid >> 3);
    const int b = logical >> 2, rt = logical & 3;
    const int tid = threadIdx.x, wave = tid >> 6, lane = tid & 63;
    const int lr = lane & 15, lk = (lane >> 4) * 8, rbase = (lane >> 4) * 4;
    const __bf16* Qb = Q  + ((size_t)b * SEQ + rt * 32) * DIM;
    const __bf16* Kb = Km + (size_t)b * SEQ * DIM;
    const __bf16* Vb = Vt + (size_t)b * DIM * SEQ;

    const int csrc = ((lane & 7) * 16) ^ (((lane >> 3) & 7) << 4);

    // ---- phase 1: S = Q K^T, chunks of BK=64 ----
    f32x4 acc[2][2] = {};
    {
        auto stage_kq = [&](int buf, int c) {
            char* Kd = smem + buf * 20480 + wave * 4096;
            char* Qd = smem + buf * 20480 + 16384 + wave * 1024;
            const char* Ks = (const char*)Kb + (size_t)(wave * 32 + (lane >> 3)) * 2048 + c * 128 + csrc;
            #pragma unroll
            for (int q = 0; q < 4; ++q)
                gload16(Ks + (size_t)q * 8 * 2048, Kd + q * 1024);
            const char* Qs = (const char*)Qb + (size_t)(wave * 8 + (lane >> 3)) * 2048 + c * 128 + csrc;
            gload16(Qs, Qd);
        };
        stage_kq(0, 0);
        WAITV(0);
        BARRIER();
        for (int c = 0; c < 16; ++c) {
            const int rb = c & 1;
            if (c < 15) stage_kq(rb ^ 1, c + 1);
            const char* Kl = smem + rb * 20480;
            const char* Ql = Kl + 16384;
            bf16x8 qf[2][2], kf[2][2];
            #pragma unroll
            for (int i = 0; i < 2; ++i)
                #pragma unroll
                for (int ks = 0; ks < 2; ++ks) {
                    const int r = i * 16 + lr;
                    qf[i][ks] = *reinterpret_cast<const bf16x8*>(
                        Ql + r * 128 + ((ks * 64 + (lane >> 4) * 16) ^ ((r & 7) << 4)));
                }
            #pragma unroll
            for (int j = 0; j < 2; ++j)
                #pragma unroll
                for (int ks = 0; ks < 2; ++ks) {
                    const int r = wave * 32 + j * 16 + lr;
                    kf[j][ks] = *reinterpret_cast<const bf16x8*>(
                        Kl + r * 128 + ((ks * 64 + (lane >> 4) * 16) ^ ((r & 7) << 4)));
                }
            __builtin_amdgcn_s_setprio(1);
            #pragma unroll
            for (int i = 0; i < 2; ++i)
                #pragma unroll
                for (int j = 0; j < 2; ++j)
                    #pragma unroll
                    for (int ks = 0; ks < 2; ++ks)
                        acc[i][j] = MFMA(qf[i][ks], kf[j][ks], acc[i][j]);
            __builtin_amdgcn_s_setprio(0);
            WAITV(0);
            BARRIER();
        }
    }
    const float scale = 0.03125f;  // 1/sqrt(1024)
    #pragma unroll
    for (int i = 0; i < 2; ++i)
        #pragma unroll
        for (int j = 0; j < 2; ++j)
            #pragma unroll
            for (int r = 0; r < 4; ++r)
                Ssh[i * 16 + rbase + r][wave * 32 + j * 16 + lr] = acc[i][j][r] * scale;
    __syncthreads();

    // ---- wave-parallel softmax ----
    {
        const int row = tid >> 3;
        const int c0  = (tid & 7) * 16;
        float4 v0 = *reinterpret_cast<const float4*>(&Ssh[row][c0]);
        float4 v1 = *reinterpret_cast<const float4*>(&Ssh[row][c0 + 4]);
        float4 v2 = *reinterpret_cast<const float4*>(&Ssh[row][c0 + 8]);
        float4 v3 = *reinterpret_cast<const float4*>(&Ssh[row][c0 + 12]);
        float e[16] = {v0.x, v0.y, v0.z, v0.w, v1.x, v1.y, v1.z, v1.w,
                       v2.x, v2.y, v2.z, v2.w, v3.x, v3.y, v3.z, v3.w};
        float mx = e[0];
        #pragma unroll
        for (int u = 1; u < 16; ++u) mx = fmaxf(mx, e[u]);
        mx = fmaxf(mx, __shfl_xor(mx, 1));
        mx = fmaxf(mx, __shfl_xor(mx, 2));
        mx = fmaxf(mx, __shfl_xor(mx, 4));
        float s = 0.f;
        #pragma unroll
        for (int u = 0; u < 16; ++u) { e[u] = __expf(e[u] - mx); s += e[u]; }
        s += __shfl_xor(s, 1);
        s += __shfl_xor(s, 2);
        s += __shfl_xor(s, 4);
        const float inv = 1.f / s;
        bf16x8 p0, p1;
        #pragma unroll
        for (int u = 0; u < 8; ++u) { p0[u] = (__bf16)(e[u] * inv); p1[u] = (__bf16)(e[u + 8] * inv); }
        *reinterpret_cast<bf16x8*>(&Psh[row][c0])     = p0;
        *reinterpret_cast<bf16x8*>(&Psh[row][c0 + 8]) = p1;
    }
    __syncthreads();

    bf16x8 pf[2][4];
    #pragma unroll
    for (int i = 0; i < 2; ++i)
        #pragma unroll
        for (int ks = 0; ks < 4; ++ks)
            pf[i][ks] = *reinterpret_cast<const bf16x8*>(&Psh[i * 16 + lr][ks * 32 + lk]);
    __syncthreads();   // pf safe in regs before buffers reused

    // ---- phase 2: att = P V ----
    __bf16* Ao = Ab + ((size_t)b * SEQ + rt * 32) * DIM;
    {
        auto stage_v = [&](int buf, int c) {
            char* Vd = smem + buf * 16384 + wave * 4096;
            #pragma unroll
            for (int q = 0; q < 4; ++q) {
                const int rowl = wave * 16 + q * 4 + (lane >> 4);
                const char* Vs = (const char*)Vb + (size_t)(c * 64 + rowl) * 256 +
                                 (((lane & 15) * 16) ^ ((rowl & 7) << 4));
                gload16(Vs, Vd + q * 1024);
            }
        };
        stage_v(0, 0);
        WAITV(0);
        BARRIER();
        for (int c = 0; c < 16; ++c) {
            const int rb = c & 1;
            if (c < 15) stage_v(rb ^ 1, c + 1);
            const char* Vl = smem + rb * 16384;
            f32x4 a2[2] = {};
            const int r = wave * 16 + lr;
            #pragma unroll
            for (int ks = 0; ks < 4; ++ks) {
                bf16x8 vf = *reinterpret_cast<const bf16x8*>(
                    Vl + r * 256 + ((ks * 64 + (lane >> 4) * 16) ^ ((r & 7) << 4)));
                a2[0] = MFMA(pf[0][ks], vf, a2[0]);
                a2[1] = MFMA(pf[1][ks], vf, a2[1]);
            }
            const int n0 = c * 64 + wave * 16;
            #pragma unroll
            for (int i = 0; i < 2; ++i)
                #pragma unroll
                for (int rr = 0; rr < 4; ++rr)
                    Ao[(size_t)(i * 16 + rbase + rr) * DIM + n0 + lr] = (__bf16)a2[i][rr];
            WAITV(8);
            BARRIER();
        }
    }
}

extern "C" void kernel_launch(void* const* d_in, const int* in_sizes, int n_in,
                              void* d_out, int out_size, void* d_ws, size_t ws_size,
                              hipStream_t stream) {
    const float* x  = (const float*)d_in[0];
    const float* Wq = (const float*)d_in[1];
    const float* bq = (const float*)d_in[2];
    const float* Wk = (const float*)d_in[3];
    const float* bk = (const float*)d_in[4];
    const float* Wv = (const float*)d_in[5];
    const float* bv = (const float*)d_in[6];
    const float* Wo = (const float*)d_in[7];
    const float* bo = (const float*)d_in[8];

    char* ws = (char*)d_ws;
    const size_t MB = 1024 * 1024;
    __bf16* Xb  = (__bf16*)(ws);              // 32MB; reused as Ab after QKV GEMM
    __bf16* Wqb = (__bf16*)(ws + 32 * MB);    // 2MB each
    __bf16* Wkb = (__bf16*)(ws + 34 * MB);
    __bf16* Wvb = (__bf16*)(ws + 36 * MB);
    __bf16* Wob = (__bf16*)(ws + 38 * MB);
    __bf16* Qb  = (__bf16*)(ws + 40 * MB);    // 32MB
    __bf16* Kb  = (__bf16*)(ws + 72 * MB);    // 32MB
    __bf16* Vt  = (__bf16*)(ws + 104 * MB);   // 32MB
    __bf16* Ab  = Xb;

    cast_all<<<dim3(8192, 2), 256, 0, stream>>>(x, Wq, Wk, Wv, Wo, Xb, Wqb, Wkb, Wvb, Wob);

    gemm_qkv3<<<768, 512, 0, stream>>>(Xb, Wqb, Wkb, Wvb, bq, bk, bv, Qb, Kb, Vt);

    attn_kernel<<<512, 256, 0, stream>>>(Qb, Kb, Vt, Ab);

    gemm_out<<<512, 512, 0, stream>>>(Ab, Wob, bo, (float*)d_out);
}

// Round 11
// 186.853 us; speedup vs baseline: 7.5125x; 1.0692x over previous
//
#include <hip/hip_runtime.h>
#include <hip/hip_bf16.h>

typedef __attribute__((ext_vector_type(8))) __bf16 bf16x8;
typedef __attribute__((ext_vector_type(4))) __bf16 bf16x4;
typedef __attribute__((ext_vector_type(4))) float f32x4;

#define SEQ 128
#define DIM 1024
#define BATCH 128
#define MTOT (BATCH * SEQ)   // 16384

// async global -> LDS, 16B per lane (global_load_lds_dwordx4)
__device__ __forceinline__ void gload16(const void* g, void* l) {
    __builtin_amdgcn_global_load_lds(
        (const __attribute__((address_space(1))) void*)g,
        (__attribute__((address_space(3))) void*)l, 16, 0, 0);
}

#define BARRIER() do { asm volatile("" ::: "memory"); __builtin_amdgcn_s_barrier(); asm volatile("" ::: "memory"); } while (0)
#define WAITV(N) asm volatile("s_waitcnt vmcnt(" #N ")" ::: "memory")
#define MFMA(a, b, c) __builtin_amdgcn_mfma_f32_16x16x32_bf16(a, b, c, 0, 0, 0)

// ---------------- one-launch cast: x (y=0) + 4 weight matrices (y=1) ----------------
__global__ void cast_all(const float* __restrict__ x,
                         const float* __restrict__ Wq, const float* __restrict__ Wk,
                         const float* __restrict__ Wv, const float* __restrict__ Wo,
                         __bf16* __restrict__ Xb,
                         __bf16* __restrict__ Wqb, __bf16* __restrict__ Wkb,
                         __bf16* __restrict__ Wvb, __bf16* __restrict__ Wob) {
    const float* src; __bf16* dst; size_t base;
    if (blockIdx.y == 0) {
        src = x; dst = Xb; base = (size_t)blockIdx.x * 2048;
    } else {
        const int j = blockIdx.x;
        if (j >= 2048) return;
        const int w = j >> 9;
        src = (w == 0) ? Wq : (w == 1) ? Wk : (w == 2) ? Wv : Wo;
        dst = (w == 0) ? Wqb : (w == 1) ? Wkb : (w == 2) ? Wvb : Wob;
        base = (size_t)(j & 511) * 2048;
    }
    const size_t i = base + (size_t)threadIdx.x * 8;
    float4 f0 = *reinterpret_cast<const float4*>(src + i);
    float4 f1 = *reinterpret_cast<const float4*>(src + i + 4);
    bf16x8 o;
    o[0] = (__bf16)f0.x; o[1] = (__bf16)f0.y; o[2] = (__bf16)f0.z; o[3] = (__bf16)f0.w;
    o[4] = (__bf16)f1.x; o[5] = (__bf16)f1.y; o[6] = (__bf16)f1.z; o[7] = (__bf16)f1.w;
    *reinterpret_cast<bf16x8*>(dst + i) = o;
}

// ======== 256x256-tile body (8 A-frags x 4 B-frags = 32 MFMA per BK=32) ========
// 4-buffer rotation: tile t reads buf[t%4], stages tile t+3 into buf[(t+3)%4] (disjoint).
// vmcnt(8) at tile end => all but the 2 newest staged tiles landed => next tile ready.
#define GEMM_TILE_BODY(RB, SB, TS, DOSTAGE, VMSTMT) do { \
    const __bf16* As_ = &lds[RB][wr][0]; \
    const __bf16* Bs_ = &lds[RB][2 + (wc >> 1)][0]; \
    const int bb_ = (wc & 1) * 64; \
    bf16x8 a0 = LDF(As_, 0 * 16 + lr), a1 = LDF(As_, 1 * 16 + lr); \
    bf16x8 a2 = LDF(As_, 2 * 16 + lr), a3 = LDF(As_, 3 * 16 + lr); \
    bf16x8 a4 = LDF(As_, 4 * 16 + lr), a5 = LDF(As_, 5 * 16 + lr); \
    bf16x8 a6 = LDF(As_, 6 * 16 + lr), a7 = LDF(As_, 7 * 16 + lr); \
    bf16x8 b0 = LDF(Bs_, bb_ + 0 * 16 + lr), b1 = LDF(Bs_, bb_ + 1 * 16 + lr); \
    bf16x8 b2 = LDF(Bs_, bb_ + 2 * 16 + lr), b3 = LDF(Bs_, bb_ + 3 * 16 + lr); \
    if (DOSTAGE) { STAGE_A(SB, TS); STAGE_B(SB, TS); } \
    __builtin_amdgcn_s_setprio(1); \
    acc[0][0] = MFMA(a0, b0, acc[0][0]); acc[0][1] = MFMA(a0, b1, acc[0][1]); \
    acc[0][2] = MFMA(a0, b2, acc[0][2]); acc[0][3] = MFMA(a0, b3, acc[0][3]); \
    acc[1][0] = MFMA(a1, b0, acc[1][0]); acc[1][1] = MFMA(a1, b1, acc[1][1]); \
    acc[1][2] = MFMA(a1, b2, acc[1][2]); acc[1][3] = MFMA(a1, b3, acc[1][3]); \
    acc[2][0] = MFMA(a2, b0, acc[2][0]); acc[2][1] = MFMA(a2, b1, acc[2][1]); \
    acc[2][2] = MFMA(a2, b2, acc[2][2]); acc[2][3] = MFMA(a2, b3, acc[2][3]); \
    acc[3][0] = MFMA(a3, b0, acc[3][0]); acc[3][1] = MFMA(a3, b1, acc[3][1]); \
    acc[3][2] = MFMA(a3, b2, acc[3][2]); acc[3][3] = MFMA(a3, b3, acc[3][3]); \
    acc[4][0] = MFMA(a4, b0, acc[4][0]); acc[4][1] = MFMA(a4, b1, acc[4][1]); \
    acc[4][2] = MFMA(a4, b2, acc[4][2]); acc[4][3] = MFMA(a4, b3, acc[4][3]); \
    acc[5][0] = MFMA(a5, b0, acc[5][0]); acc[5][1] = MFMA(a5, b1, acc[5][1]); \
    acc[5][2] = MFMA(a5, b2, acc[5][2]); acc[5][3] = MFMA(a5, b3, acc[5][3]); \
    acc[6][0] = MFMA(a6, b0, acc[6][0]); acc[6][1] = MFMA(a6, b1, acc[6][1]); \
    acc[6][2] = MFMA(a6, b2, acc[6][2]); acc[6][3] = MFMA(a6, b3, acc[6][3]); \
    acc[7][0] = MFMA(a7, b0, acc[7][0]); acc[7][1] = MFMA(a7, b1, acc[7][1]); \
    acc[7][2] = MFMA(a7, b2, acc[7][2]); acc[7][3] = MFMA(a7, b3, acc[7][3]); \
    __builtin_amdgcn_s_setprio(0); \
    VMSTMT; \
    BARRIER(); \
} while (0)

#define GEMM_MAIN_LOOP() do { \
    STAGE_A(0, 0); STAGE_B(0, 0); \
    STAGE_A(1, 1); STAGE_B(1, 1); \
    STAGE_A(2, 2); STAGE_B(2, 2); \
    WAITV(8); \
    BARRIER(); \
    for (int it = 0; it < 7; ++it) { \
        const int t = it * 4; \
        GEMM_TILE_BODY(0, 3, t + 3, 1, WAITV(8)); \
        GEMM_TILE_BODY(1, 0, t + 4, 1, WAITV(8)); \
        GEMM_TILE_BODY(2, 1, t + 5, 1, WAITV(8)); \
        GEMM_TILE_BODY(3, 2, t + 6, 1, WAITV(8)); \
    } \
    GEMM_TILE_BODY(0, 3, 31, 1, WAITV(8));   /* tile 28 stages 31 */ \
    GEMM_TILE_BODY(1, 0, 0, 0, WAITV(4));    /* tile 29 */ \
    GEMM_TILE_BODY(2, 0, 0, 0, WAITV(0));    /* tile 30 */ \
    GEMM_TILE_BODY(3, 0, 0, 0, (void)0);     /* tile 31 */ \
} while (0)

// ---------------- fused QKV GEMM: 256x256 tiles, 4-buf (128KB), stage-3-ahead ----------------
// Grid 768: XCD-swizzled logical = mt*12 + nt; nt>>2 selects {Q,K,V}; V written per-batch transposed.
__global__ __launch_bounds__(512, 1) void gemm_qkv3(const __bf16* __restrict__ A,
        const __bf16* __restrict__ Wqb, const __bf16* __restrict__ Wkb, const __bf16* __restrict__ Wvb,
        const float* __restrict__ bq, const float* __restrict__ bk, const float* __restrict__ bv,
        __bf16* __restrict__ Qo, __bf16* __restrict__ Ko, __bf16* __restrict__ Vt) {
    const int K = 1024;
    __shared__ __bf16 lds[4][4][4096];   // 128KB
    const int tid = threadIdx.x, wave = tid >> 6, lane = tid & 63;
    const int wr = wave >> 2, wc = wave & 3;
    const int lr = lane & 15;
    const int lkb = ((lane >> 4) & 3) * 16;
    const unsigned bid = blockIdx.x;
    const unsigned swz = (bid & 7) * 96 + (bid >> 3);
    const int mt = swz / 12, nt = swz % 12;
    const int m0 = mt * 256;
    const int n0row = (nt & 3) * 256;
    const int mid = nt >> 2;                  // 0=Q 1=K 2=V
    const __bf16* Wsel = (mid == 0) ? Wqb : (mid == 1) ? Wkb : Wvb;
    const float*  bsel = (mid == 0) ? bq  : (mid == 1) ? bk  : bv;

    const int rloc = wave * 16 + (lane >> 2);
    const int cbs  = ((((lane & 3) << 4) ^ (((lane >> 3) & 3) << 4)) >> 1);
    const __bf16* pA = A + (size_t)(m0 + rloc) * K + cbs;
    const __bf16* pB = Wsel + (size_t)(n0row + rloc) * K + cbs;
    const int wo = wave * 512;

    f32x4 acc[8][4] = {};

#define LDF(SLOT, R) (*reinterpret_cast<const bf16x8*>( \
        reinterpret_cast<const char*>(SLOT) + (R) * 64 + (lkb ^ ((((R) >> 1) & 3) << 4))))
#define STAGE_A(SB, TS) do { gload16(pA + (TS) * 32, &lds[SB][0][wo]); \
                             gload16(pA + (size_t)128 * 1024 + (TS) * 32, &lds[SB][1][wo]); } while (0)
#define STAGE_B(SB, TS) do { gload16(pB + (TS) * 32, &lds[SB][2][wo]); \
                             gload16(pB + (size_t)128 * 1024 + (TS) * 32, &lds[SB][3][wo]); } while (0)

    GEMM_MAIN_LOOP();

    const int rbase = (lane >> 4) * 4;
    #pragma unroll
    for (int ri = 0; ri < 8; ++ri) {
        #pragma unroll
        for (int j = 0; j < 4; ++j) {
            const int gcl = n0row + wc * 64 + j * 16 + lr;
            const float bvv = bsel[gcl];
            const int grb = m0 + wr * 128 + ri * 16 + rbase;
            if (mid < 2) {
                __bf16* C = (mid == 0) ? Qo : Ko;
                #pragma unroll
                for (int r = 0; r < 4; ++r)
                    C[(size_t)(grb + r) * DIM + gcl] = (__bf16)(acc[ri][j][r] + bvv);
            } else {
                const int b = grb >> 7, s = grb & 127;
                bf16x4 v;
                #pragma unroll
                for (int r = 0; r < 4; ++r) v[r] = (__bf16)(acc[ri][j][r] + bvv);
                *reinterpret_cast<bf16x4*>(&Vt[((size_t)b * DIM + gcl) * SEQ + s]) = v;
            }
        }
    }
#undef STAGE_A
#undef STAGE_B
#undef LDF
}

// ---------------- output GEMM: 256x256 tiles, 4-buf (128KB), MODE f32 out, grid 256 ----------------
__global__ __launch_bounds__(512, 1) void gemm256o(const __bf16* __restrict__ A,
                                                   const __bf16* __restrict__ W,
                                                   const float* __restrict__ bias,
                                                   float* __restrict__ Cout) {
    const int K = 1024, N = 1024;
    __shared__ __bf16 lds[4][4][4096];   // 128KB
    const int tid = threadIdx.x, wave = tid >> 6, lane = tid & 63;
    const int wr = wave >> 2, wc = wave & 3;
    const int lr = lane & 15;
    const int lkb = ((lane >> 4) & 3) * 16;
    const int bid = blockIdx.x;
    const int swz = (bid & 7) * 32 + (bid >> 3);
    const int m0 = (swz >> 2) * 256, n0 = (swz & 3) * 256;
    const int rloc = wave * 16 + (lane >> 2);
    const int cbs  = ((((lane & 3) << 4) ^ (((lane >> 3) & 3) << 4)) >> 1);
    const __bf16* pA = A + (size_t)(m0 + rloc) * K + cbs;
    const __bf16* pB = W + (size_t)(n0 + rloc) * K + cbs;
    const int wo = wave * 512;

    f32x4 acc[8][4] = {};

#define LDF(SLOT, R) (*reinterpret_cast<const bf16x8*>( \
        reinterpret_cast<const char*>(SLOT) + (R) * 64 + (lkb ^ ((((R) >> 1) & 3) << 4))))
#define STAGE_A(SB, TS) do { gload16(pA + (TS) * 32, &lds[SB][0][wo]); \
                             gload16(pA + (size_t)128 * 1024 + (TS) * 32, &lds[SB][1][wo]); } while (0)
#define STAGE_B(SB, TS) do { gload16(pB + (TS) * 32, &lds[SB][2][wo]); \
                             gload16(pB + (size_t)128 * 1024 + (TS) * 32, &lds[SB][3][wo]); } while (0)

    GEMM_MAIN_LOOP();

    const int rbase = (lane >> 4) * 4;
    #pragma unroll
    for (int ri = 0; ri < 8; ++ri) {
        #pragma unroll
        for (int j = 0; j < 4; ++j) {
            const int gc  = n0 + wc * 64 + j * 16 + lr;
            const float bv = bias[gc];
            const int grb = m0 + wr * 128 + ri * 16 + rbase;
            #pragma unroll
            for (int r = 0; r < 4; ++r)
                Cout[(size_t)(grb + r) * N + gc] = acc[ri][j][r] + bv;
        }
    }
#undef STAGE_A
#undef STAGE_B
#undef LDF
}

// ---------------- fused attention, LDS-pipelined (unchanged from round 4/7) ----------------
__global__ __launch_bounds__(256) void attn_kernel(const __bf16* __restrict__ Q,
                                                   const __bf16* __restrict__ Km,
                                                   const __bf16* __restrict__ Vt,
                                                   __bf16* __restrict__ Ab) {
    __shared__ __align__(16) char smem[40960];
    float  (*Ssh)[132] = (float(*)[132])(smem);            // [32][132] f32
    __bf16 (*Psh)[136] = (__bf16(*)[136])(smem + 16896);   // [32][136] bf16

    const int bid = blockIdx.x;
    const int logical = (bid & 7) * 64 + (bid >> 3);
    const int b = logical >> 2, rt = logical & 3;
    const int tid = threadIdx.x, wave = tid >> 6, lane = tid & 63;
    const int lr = lane & 15, lk = (lane >> 4) * 8, rbase = (lane >> 4) * 4;
    const __bf16* Qb = Q  + ((size_t)b * SEQ + rt * 32) * DIM;
    const __bf16* Kb = Km + (size_t)b * SEQ * DIM;
    const __bf16* Vb = Vt + (size_t)b * DIM * SEQ;

    const int csrc = ((lane & 7) * 16) ^ (((lane >> 3) & 7) << 4);

    // ---- phase 1: S = Q K^T, chunks of BK=64 ----
    f32x4 acc[2][2] = {};
    {
        auto stage_kq = [&](int buf, int c) {
            char* Kd = smem + buf * 20480 + wave * 4096;
            char* Qd = smem + buf * 20480 + 16384 + wave * 1024;
            const char* Ks = (const char*)Kb + (size_t)(wave * 32 + (lane >> 3)) * 2048 + c * 128 + csrc;
            #pragma unroll
            for (int q = 0; q < 4; ++q)
                gload16(Ks + (size_t)q * 8 * 2048, Kd + q * 1024);
            const char* Qs = (const char*)Qb + (size_t)(wave * 8 + (lane >> 3)) * 2048 + c * 128 + csrc;
            gload16(Qs, Qd);
        };
        stage_kq(0, 0);
        WAITV(0);
        BARRIER();
        for (int c = 0; c < 16; ++c) {
            const int rb = c & 1;
            if (c < 15) stage_kq(rb ^ 1, c + 1);
            const char* Kl = smem + rb * 20480;
            const char* Ql = Kl + 16384;
            bf16x8 qf[2][2], kf[2][2];
            #pragma unroll
            for (int i = 0; i < 2; ++i)
                #pragma unroll
                for (int ks = 0; ks < 2; ++ks) {
                    const int r = i * 16 + lr;
                    qf[i][ks] = *reinterpret_cast<const bf16x8*>(
                        Ql + r * 128 + ((ks * 64 + (lane >> 4) * 16) ^ ((r & 7) << 4)));
                }
            #pragma unroll
            for (int j = 0; j < 2; ++j)
                #pragma unroll
                for (int ks = 0; ks < 2; ++ks) {
                    const int r = wave * 32 + j * 16 + lr;
                    kf[j][ks] = *reinterpret_cast<const bf16x8*>(
                        Kl + r * 128 + ((ks * 64 + (lane >> 4) * 16) ^ ((r & 7) << 4)));
                }
            __builtin_amdgcn_s_setprio(1);
            #pragma unroll
            for (int i = 0; i < 2; ++i)
                #pragma unroll
                for (int j = 0; j < 2; ++j)
                    #pragma unroll
                    for (int ks = 0; ks < 2; ++ks)
                        acc[i][j] = MFMA(qf[i][ks], kf[j][ks], acc[i][j]);
            __builtin_amdgcn_s_setprio(0);
            WAITV(0);
            BARRIER();
        }
    }
    const float scale = 0.03125f;  // 1/sqrt(1024)
    #pragma unroll
    for (int i = 0; i < 2; ++i)
        #pragma unroll
        for (int j = 0; j < 2; ++j)
            #pragma unroll
            for (int r = 0; r < 4; ++r)
                Ssh[i * 16 + rbase + r][wave * 32 + j * 16 + lr] = acc[i][j][r] * scale;
    __syncthreads();

    // ---- wave-parallel softmax ----
    {
        const int row = tid >> 3;
        const int c0  = (tid & 7) * 16;
        float4 v0 = *reinterpret_cast<const float4*>(&Ssh[row][c0]);
        float4 v1 = *reinterpret_cast<const float4*>(&Ssh[row][c0 + 4]);
        float4 v2 = *reinterpret_cast<const float4*>(&Ssh[row][c0 + 8]);
        float4 v3 = *reinterpret_cast<const float4*>(&Ssh[row][c0 + 12]);
        float e[16] = {v0.x, v0.y, v0.z, v0.w, v1.x, v1.y, v1.z, v1.w,
                       v2.x, v2.y, v2.z, v2.w, v3.x, v3.y, v3.z, v3.w};
        float mx = e[0];
        #pragma unroll
        for (int u = 1; u < 16; ++u) mx = fmaxf(mx, e[u]);
        mx = fmaxf(mx, __shfl_xor(mx, 1));
        mx = fmaxf(mx, __shfl_xor(mx, 2));
        mx = fmaxf(mx, __shfl_xor(mx, 4));
        float s = 0.f;
        #pragma unroll
        for (int u = 0; u < 16; ++u) { e[u] = __expf(e[u] - mx); s += e[u]; }
        s += __shfl_xor(s, 1);
        s += __shfl_xor(s, 2);
        s += __shfl_xor(s, 4);
        const float inv = 1.f / s;
        bf16x8 p0, p1;
        #pragma unroll
        for (int u = 0; u < 8; ++u) { p0[u] = (__bf16)(e[u] * inv); p1[u] = (__bf16)(e[u + 8] * inv); }
        *reinterpret_cast<bf16x8*>(&Psh[row][c0])     = p0;
        *reinterpret_cast<bf16x8*>(&Psh[row][c0 + 8]) = p1;
    }
    __syncthreads();

    bf16x8 pf[2][4];
    #pragma unroll
    for (int i = 0; i < 2; ++i)
        #pragma unroll
        for (int ks = 0; ks < 4; ++ks)
            pf[i][ks] = *reinterpret_cast<const bf16x8*>(&Psh[i * 16 + lr][ks * 32 + lk]);
    __syncthreads();   // pf safe in regs before buffers reused

    // ---- phase 2: att = P V ----
    __bf16* Ao = Ab + ((size_t)b * SEQ + rt * 32) * DIM;
    {
        auto stage_v = [&](int buf, int c) {
            char* Vd = smem + buf * 16384 + wave * 4096;
            #pragma unroll
            for (int q = 0; q < 4; ++q) {
                const int rowl = wave * 16 + q * 4 + (lane >> 4);
                const char* Vs = (const char*)Vb + (size_t)(c * 64 + rowl) * 256 +
                                 (((lane & 15) * 16) ^ ((rowl & 7) << 4));
                gload16(Vs, Vd + q * 1024);
            }
        };
        stage_v(0, 0);
        WAITV(0);
        BARRIER();
        for (int c = 0; c < 16; ++c) {
            const int rb = c & 1;
            if (c < 15) stage_v(rb ^ 1, c + 1);
            const char* Vl = smem + rb * 16384;
            f32x4 a2[2] = {};
            const int r = wave * 16 + lr;
            #pragma unroll
            for (int ks = 0; ks < 4; ++ks) {
                bf16x8 vf = *reinterpret_cast<const bf16x8*>(
                    Vl + r * 256 + ((ks * 64 + (lane >> 4) * 16) ^ ((r & 7) << 4)));
                a2[0] = MFMA(pf[0][ks], vf, a2[0]);
                a2[1] = MFMA(pf[1][ks], vf, a2[1]);
            }
            const int n0 = c * 64 + wave * 16;
            #pragma unroll
            for (int i = 0; i < 2; ++i)
                #pragma unroll
                for (int rr = 0; rr < 4; ++rr)
                    Ao[(size_t)(i * 16 + rbase + rr) * DIM + n0 + lr] = (__bf16)a2[i][rr];
            WAITV(8);
            BARRIER();
        }
    }
}

extern "C" void kernel_launch(void* const* d_in, const int* in_sizes, int n_in,
                              void* d_out, int out_size, void* d_ws, size_t ws_size,
                              hipStream_t stream) {
    const float* x  = (const float*)d_in[0];
    const float* Wq = (const float*)d_in[1];
    const float* bq = (const float*)d_in[2];
    const float* Wk = (const float*)d_in[3];
    const float* bk = (const float*)d_in[4];
    const float* Wv = (const float*)d_in[5];
    const float* bv = (const float*)d_in[6];
    const float* Wo = (const float*)d_in[7];
    const float* bo = (const float*)d_in[8];

    char* ws = (char*)d_ws;
    const size_t MB = 1024 * 1024;
    __bf16* Xb  = (__bf16*)(ws);              // 32MB; reused as Ab after QKV GEMM
    __bf16* Wqb = (__bf16*)(ws + 32 * MB);    // 2MB each
    __bf16* Wkb = (__bf16*)(ws + 34 * MB);
    __bf16* Wvb = (__bf16*)(ws + 36 * MB);
    __bf16* Wob = (__bf16*)(ws + 38 * MB);
    __bf16* Qb  = (__bf16*)(ws + 40 * MB);    // 32MB
    __bf16* Kb  = (__bf16*)(ws + 72 * MB);    // 32MB
    __bf16* Vt  = (__bf16*)(ws + 104 * MB);   // 32MB
    __bf16* Ab  = Xb;

    cast_all<<<dim3(8192, 2), 256, 0, stream>>>(x, Wq, Wk, Wv, Wo, Xb, Wqb, Wkb, Wvb, Wob);

    gemm_qkv3<<<768, 512, 0, stream>>>(Xb, Wqb, Wkb, Wvb, bq, bk, bv, Qb, Kb, Vt);

    attn_kernel<<<512, 256, 0, stream>>>(Qb, Kb, Vt, Ab);

    gemm256o<<<256, 512, 0, stream>>>(Ab, Wob, bo, (float*)d_out);
}